// Round 18
// baseline (248.072 us; speedup 1.0000x reference)
//
#include <hip/hip_runtime.h>
#include <stdint.h>

typedef _Float16 f16;
typedef f16 f16x4 __attribute__((ext_vector_type(4)));
typedef f16 f16x8 __attribute__((ext_vector_type(8)));
typedef float f32x4 __attribute__((ext_vector_type(4)));

constexpr float SCALE = 0.08838834764831845f; // 1/sqrt(128)

__device__ __forceinline__ void glds16(const void* g, void* l) {
  __builtin_amdgcn_global_load_lds(
      (const __attribute__((address_space(1))) void*)g,
      (__attribute__((address_space(3))) void*)l, 16, 0, 0);
}
__device__ __forceinline__ void glds4(const void* g, void* l) {
  __builtin_amdgcn_global_load_lds(
      (const __attribute__((address_space(1))) void*)g,
      (__attribute__((address_space(3))) void*)l, 4, 0, 0);
}

// ---------------- projection (NT feature loads):
__global__ __launch_bounds__(256) void proj_kernel(
    const float* __restrict__ f1, const float* __restrict__ f2,
    const float* __restrict__ W1, const float* __restrict__ b1,
    const float* __restrict__ W2, const float* __restrict__ b2,
    f16* __restrict__ q_h, f16* __restrict__ k_h,
    f16* __restrict__ f1t, f16* __restrict__ f2t)
{
  __shared__ f16 a_lds[128 * 128];
  __shared__ f16 w_lds[128 * 128];

  const int tid = threadIdx.x;
  const int blk = blockIdx.x;
  const bool qside = blk < 512;
  const float* feat = qside ? f1 : f2;
  const float* W    = qside ? W1 : W2;
  const float* bias = qside ? b1 : b2;
  f16* op = qside ? q_h : k_h;
  f16* ft = qside ? f1t : f2t;
  const size_t row0 = (size_t)(qside ? blk : blk - 512) * 128;

  for (int it = 0; it < 16; ++it) {
    int u = tid + it * 256;
    int r = u >> 5;
    int c4 = (u & 31) * 4;
    f32x4 v = __builtin_nontemporal_load(
        (const f32x4*)&feat[(row0 + r) * 128 + c4]);
    f16x4 h4 = { (f16)v[0], (f16)v[1], (f16)v[2], (f16)v[3] };
    int adr = r * 128 + ((((c4 >> 3) ^ (r & 7)) << 3) | (c4 & 7));
    *(f16x4*)&a_lds[adr] = h4;
    float4 wv = *(const float4*)&W[r * 128 + c4];
    f16x4 wh = { (f16)wv.x, (f16)wv.y, (f16)wv.z, (f16)wv.w };
    *(f16x4*)&w_lds[adr] = wh;
  }
  __syncthreads();

  const int w = tid >> 6, l = tid & 63, lam = l & 15, g = l >> 4;
  f32x4 acc[2][8] = {};
#pragma unroll
  for (int kc = 0; kc < 4; ++kc) {
    f16x8 a[2];
#pragma unroll
    for (int rf = 0; rf < 2; ++rf) {
      int ar = w * 32 + rf * 16 + lam;
      a[rf] = *(const f16x8*)&a_lds[ar * 128 + (((4 * kc + g) ^ (ar & 7)) << 3)];
    }
#pragma unroll
    for (int cf = 0; cf < 8; ++cf) {
      int br = cf * 16 + lam;
      f16x8 bfr = *(const f16x8*)&w_lds[br * 128 + (((4 * kc + g) ^ (br & 7)) << 3)];
      acc[0][cf] = __builtin_amdgcn_mfma_f32_16x16x32_f16(a[0], bfr, acc[0][cf], 0, 0, 0);
      acc[1][cf] = __builtin_amdgcn_mfma_f32_16x16x32_f16(a[1], bfr, acc[1][cf], 0, 0, 0);
    }
  }
#pragma unroll
  for (int cf = 0; cf < 8; ++cf) {
    int col = cf * 16 + lam;
    float bv = bias[col];
#pragma unroll
    for (int rf = 0; rf < 2; ++rf)
#pragma unroll
      for (int i = 0; i < 4; ++i) {
        size_t grow = row0 + w * 32 + rf * 16 + g * 4 + i;
        op[grow * 128 + col] = (f16)(acc[rf][cf][i] + bv);
      }
  }

  { // transposed feature write: ft[b][f][l]
    const int b = (int)(row0 >> 10);
    const int l0 = (int)(row0 & 1023);
    const int f = tid >> 1;
    const int half = tid & 1;
    f16 buf[64];
#pragma unroll
    for (int j = 0; j < 64; ++j) {
      int r = half * 64 + j;
      buf[j] = a_lds[r * 128 + ((((f >> 3) ^ (r & 7)) << 3) | (f & 7))];
    }
    f16* dst = ft + ((size_t)b * 128 + f) * 1024 + l0 + half * 64;
#pragma unroll
    for (int c = 0; c < 8; ++c)
      *(f16x8*)&dst[c * 8] = *(const f16x8*)&buf[c * 8];
  }
}

// ---------------- attn PASS 0, QBLK=64, grid 1024 (r17-verified body).
// T4 counted-vmcnt pipeline: barrier1 = raw s_barrier (exec-only);
// mask(kt+1) glds16 issues BEFORE barrier2; barrier2 = vmcnt(4)+s_barrier
// (drains KV(kt)+mask(kt)+store, leaves 4 mask loads flying a full tile).
__global__ __launch_bounds__(256, 2) void attn0_kernel(
    const f16* __restrict__ Qh, const f16* __restrict__ Kh,
    const f16* __restrict__ Vt, const int* __restrict__ mask,
    uint32_t* __restrict__ bits, float* __restrict__ outp)
{
  __shared__ f16 k_lds[64 * 128];   // 16 KB
  __shared__ f16 v_lds[128 * 64];   // 16 KB
  __shared__ f16 p_lds[4 * 16 * 72];// 9 KB
  __shared__ int m_lds[2][64 * 64]; // 32 KB raw mask tiles

  const int tid = threadIdx.x;
  const int u = blockIdx.x;
  const int qt = (u >> 3) & 15;
  const int b = ((u >> 7) << 3) | (u & 7);
  const int w = tid >> 6, l = tid & 63, lam = l & 15, g = l >> 4;
  const size_t batch_row = (size_t)b << 10;
  const f16* vtb = Vt + ((size_t)b << 17);

  f16x8 qf[4];
  {
    const f16* qbase = Qh + (batch_row + qt * 64 + w * 16 + lam) * 128;
#pragma unroll
    for (int kc = 0; kc < 4; ++kc) qf[kc] = *(const f16x8*)&qbase[kc * 32 + g * 8];
  }

  auto stageMask = [&](int kt_, int bu) {
#pragma unroll
    for (int it = 0; it < 4; ++it) {
      int slot0 = (w * 4 + it) * 64;
      int i = slot0 + l;
      int r = i >> 4, cd = i & 15;
      int cg = cd ^ (r & 7);
      glds16(mask + (batch_row + qt * 64 + r) * 1024 + kt_ * 64 + cg * 4,
             &m_lds[bu][slot0 * 4]);
    }
  };

  f32x4 acc[8] = {};
  float mrun[4], lrun[4];
#pragma unroll
  for (int i = 0; i < 4; ++i) { mrun[i] = -__builtin_inff(); lrun[i] = 0.f; }

  stageMask(0, 0); // prologue: tile-0 mask in flight

  int c = 0;
  for (int kt = 0; kt < 16; ++kt) {
    const int kb = kt * 64;
    __builtin_amdgcn_s_barrier(); // barrier1: exec-only (LDS reads drained by dataflow)

    { // stage K tile (8 glds16/thread total with V)
      const f16* kbase = Kh + (batch_row + kb) * 128;
#pragma unroll
      for (int it = 0; it < 4; ++it) {
        int slot0 = (w * 4 + it) * 64;
        int i = slot0 + l;
        int r = i >> 4, ch = i & 15;
        glds16(kbase + r * 128 + ((ch ^ (r & 7)) << 3), &k_lds[slot0 * 8]);
      }
    }
    { // stage V^T tile
#pragma unroll
      for (int it = 0; it < 4; ++it) {
        int slot0 = (w * 4 + it) * 64;
        int i = slot0 + l;
        int r = i >> 3, ch = i & 7;
        glds16(vtb + r * 1024 + kb + ((ch ^ (r & 7)) << 3), &v_lds[slot0 * 8]);
      }
    }
    // issue next mask tile BEFORE barrier2 (kt==15: dummy re-stage keeps
    // vmcnt counts uniform; buffer never read)
    stageMask(kt < 15 ? kt + 1 : 15, c ^ 1);

    // barrier2: drain store(kt-1)+KV(kt)+mask(kt), leave mask(kt+1) flying
    asm volatile("s_waitcnt vmcnt(4)" ::: "memory");
    __builtin_amdgcn_s_barrier();

    // QK^T
    f32x4 sv[4] = {};
    __builtin_amdgcn_s_setprio(1);
#pragma unroll
    for (int kc = 0; kc < 4; ++kc) {
#pragma unroll
      for (int cf = 0; cf < 4; ++cf) {
        int br = cf * 16 + lam;
        f16x8 bk = *(const f16x8*)&k_lds[br * 128 + (((4 * kc + g) ^ (br & 7)) << 3)];
        sv[cf] = __builtin_amdgcn_mfma_f32_16x16x32_f16(qf[kc], bk, sv[cf], 0, 0, 0);
      }
    }
    __builtin_amdgcn_s_setprio(0);

    // gather mask from raw int tile (swizzled read)
    uint32_t mk = 0;
#pragma unroll
    for (int cf = 0; cf < 4; ++cf)
#pragma unroll
      for (int ii = 0; ii < 4; ++ii) {
        int rt = w * 16 + g * 4 + ii;
        int cc = cf * 16 + lam;
        int mv = m_lds[c][rt * 64 + (cc ^ ((rt & 7) << 2))];
        mk |= (mv != 0 ? 1u : 0u) << (cf * 4 + ii);
      }

    // ballot-pack standard-layout bits for pass 1
    uint64_t B00 = __ballot((mk >> 0) & 1),  B01 = __ballot((mk >> 1) & 1);
    uint64_t B02 = __ballot((mk >> 2) & 1),  B03 = __ballot((mk >> 3) & 1);
    uint64_t B10 = __ballot((mk >> 4) & 1),  B11 = __ballot((mk >> 5) & 1);
    uint64_t B12 = __ballot((mk >> 6) & 1),  B13 = __ballot((mk >> 7) & 1);
    uint64_t B20 = __ballot((mk >> 8) & 1),  B21 = __ballot((mk >> 9) & 1);
    uint64_t B22 = __ballot((mk >> 10) & 1), B23 = __ballot((mk >> 11) & 1);
    uint64_t B30 = __ballot((mk >> 12) & 1), B31 = __ballot((mk >> 13) & 1);
    uint64_t B32 = __ballot((mk >> 14) & 1), B33 = __ballot((mk >> 15) & 1);
    if (l < 32) {
      int rl = l >> 1, half = l & 1;
      int gp = rl >> 2, ip = rl & 3;
      uint64_t a0 = half ? B20 : B00, a1 = half ? B21 : B01;
      uint64_t a2 = half ? B22 : B02, a3 = half ? B23 : B03;
      uint64_t t0 = (ip & 1) ? a1 : a0, t1 = (ip & 1) ? a3 : a2;
      uint64_t sLo = (ip & 2) ? t1 : t0;
      uint64_t b0 = half ? B30 : B10, b1 = half ? B31 : B11;
      uint64_t b2 = half ? B32 : B12, b3 = half ? B33 : B13;
      uint64_t u0 = (ip & 1) ? b1 : b0, u1 = (ip & 1) ? b3 : b2;
      uint64_t sHi = (ip & 2) ? u1 : u0;
      uint32_t lo16 = (uint32_t)(sLo >> (gp * 16)) & 0xFFFFu;
      uint32_t hi16 = (uint32_t)(sHi >> (gp * 16)) & 0xFFFFu;
      bits[(batch_row + qt * 64 + w * 16 + rl) * 32 + kt * 2 + half] =
          lo16 | (hi16 << 16);
    }

    // online softmax over kv cols
    float mrow4[4];
#pragma unroll
    for (int i = 0; i < 4; ++i) mrow4[i] = -1e30f;
#pragma unroll
    for (int cf = 0; cf < 4; ++cf)
#pragma unroll
      for (int i = 0; i < 4; ++i) {
        float v = sv[cf][i] * SCALE;
        sv[cf][i] = v;
        mrow4[i] = fmaxf(mrow4[i], ((mk >> (cf * 4 + i)) & 1u) ? v : -1e30f);
      }
#pragma unroll
    for (int d = 1; d <= 8; d <<= 1)
#pragma unroll
      for (int i = 0; i < 4; ++i)
        mrow4[i] = fmaxf(mrow4[i], __shfl_xor(mrow4[i], d, 64));

    float sf[4], lsum[4];
#pragma unroll
    for (int i = 0; i < 4; ++i) {
      float mn = fmaxf(mrun[i], mrow4[i]);
      sf[i] = __expf(mrun[i] - mn);
      mrun[i] = mn;
      lsum[i] = 0.f;
    }
    f16* pslice = &p_lds[w * 1152];
#pragma unroll
    for (int cf = 0; cf < 4; ++cf)
#pragma unroll
      for (int i = 0; i < 4; ++i) {
        float p = ((mk >> (cf * 4 + i)) & 1u) ? __expf(sv[cf][i] - mrun[i]) : 0.f;
        lsum[i] += p;
        int row = g * 4 + i;
        int cchunk = 2 * cf + (lam >> 3);
        pslice[row * 72 + (((cchunk ^ (row & 7)) << 3) | (lam & 7))] = (f16)p;
      }
#pragma unroll
    for (int d = 1; d <= 8; d <<= 1)
#pragma unroll
      for (int i = 0; i < 4; ++i)
        lsum[i] += __shfl_xor(lsum[i], d, 64);
#pragma unroll
    for (int i = 0; i < 4; ++i) lrun[i] = lrun[i] * sf[i] + lsum[i];
#pragma unroll
    for (int nf = 0; nf < 8; ++nf)
#pragma unroll
      for (int i = 0; i < 4; ++i) acc[nf][i] *= sf[i];

    // PV
    __builtin_amdgcn_s_setprio(1);
#pragma unroll
    for (int kc2 = 0; kc2 < 2; ++kc2) {
      f16x8 ap = *(const f16x8*)&pslice[lam * 72 + (((4 * kc2 + g) ^ (lam & 7)) << 3)];
#pragma unroll
      for (int nf = 0; nf < 8; ++nf) {
        int vr = nf * 16 + lam;
        f16x8 bv = *(const f16x8*)&v_lds[vr * 64 + (((kc2 * 4 + g) ^ (vr & 7)) << 3)];
        acc[nf] = __builtin_amdgcn_mfma_f32_16x16x32_f16(ap, bv, acc[nf], 0, 0, 0);
      }
    }
    __builtin_amdgcn_s_setprio(0);
    c ^= 1;
  }

  float inv[4];
#pragma unroll
  for (int i = 0; i < 4; ++i) inv[i] = (lrun[i] > 0.f) ? 1.f / lrun[i] : 0.f;
  const size_t orow0 = batch_row + (size_t)qt * 64 + w * 16;
#pragma unroll
  for (int nf = 0; nf < 8; ++nf)
#pragma unroll
    for (int i = 0; i < 4; ++i)
      __builtin_nontemporal_store(acc[nf][i] * inv[i],
          &outp[(orow0 + g * 4 + i) * 128 + nf * 16 + lam]);
}

// ---------------- attn PASS 1, QBLK=128, grid 512 (r14-verified, bits input)
__global__ __launch_bounds__(256, 2) void attn1_kernel(
    const f16* __restrict__ Qh, const f16* __restrict__ Kh,
    const f16* __restrict__ Vt, const uint32_t* __restrict__ bits,
    float* __restrict__ outp)
{
  __shared__ f16 k_lds[64 * 128];
  __shared__ f16 v_lds[128 * 64];
  __shared__ f16 p_lds[8 * 16 * 72];
  __shared__ uint32_t mb[256];

  const int tid = threadIdx.x;
  const int u = blockIdx.x;
  const int qt = (u >> 3) & 7;
  const int b = ((u >> 6) << 3) | (u & 7);
  const int w = tid >> 6, l = tid & 63, lam = l & 15, g = l >> 4;
  const size_t batch_row = (size_t)b << 10;

  f16x8 qf[2][4];
#pragma unroll
  for (int qd = 0; qd < 2; ++qd) {
    const f16* qbase = Qh + (batch_row + qt * 128 + w * 32 + qd * 16 + lam) * 128;
#pragma unroll
    for (int kc = 0; kc < 4; ++kc) qf[qd][kc] = *(const f16x8*)&qbase[kc * 32 + g * 8];
  }

  f32x4 acc[2][8] = {};
  float mrun[2][4], lrun[2][4];
#pragma unroll
  for (int qd = 0; qd < 2; ++qd)
#pragma unroll
    for (int i = 0; i < 4; ++i) { mrun[qd][i] = -__builtin_inff(); lrun[qd][i] = 0.f; }

  const f16* vtb = Vt + ((size_t)b << 17);

  for (int kt = 0; kt < 16; ++kt) {
    const int kb = kt * 64;
    __syncthreads();
    {
      const f16* kbase = Kh + (batch_row + kb) * 128;
#pragma unroll
      for (int it = 0; it < 4; ++it) {
        int slot0 = (w * 4 + it) * 64;
        int i = slot0 + l;
        int r = i >> 4, ch = i & 15;
        glds16(kbase + r * 128 + ((ch ^ (r & 7)) << 3), &k_lds[slot0 * 8]);
      }
    }
    {
#pragma unroll
      for (int it = 0; it < 4; ++it) {
        int slot0 = (w * 4 + it) * 64;
        int i = slot0 + l;
        int r = i >> 3, ch = i & 7;
        glds16(vtb + r * 1024 + kb + ((ch ^ (r & 7)) << 3), &v_lds[slot0 * 8]);
      }
    }
    {
      int idx = w * 64 + l;
      glds4(bits + (batch_row + kb + (idx >> 2)) * 32 + qt * 4 + (l & 3),
            &mb[w * 64]);
    }
    __syncthreads();

#pragma unroll
    for (int qd = 0; qd < 2; ++qd) {
      f32x4 sv[4] = {};
      __builtin_amdgcn_s_setprio(1);
#pragma unroll
      for (int kc = 0; kc < 4; ++kc) {
#pragma unroll
        for (int cf = 0; cf < 4; ++cf) {
          int br = cf * 16 + lam;
          f16x8 bk = *(const f16x8*)&k_lds[br * 128 + (((4 * kc + g) ^ (br & 7)) << 3)];
          sv[cf] = __builtin_amdgcn_mfma_f32_16x16x32_f16(qf[qd][kc], bk, sv[cf], 0, 0, 0);
        }
      }
      __builtin_amdgcn_s_setprio(0);

      uint32_t mk = 0;
#pragma unroll
      for (int cf = 0; cf < 4; ++cf) {
        uint32_t wd = mb[(cf * 16 + lam) * 4 + w];
#pragma unroll
        for (int i = 0; i < 4; ++i)
          mk |= ((wd >> (qd * 16 + g * 4 + i)) & 1u) << (cf * 4 + i);
      }

      float mrow4[4];
#pragma unroll
      for (int i = 0; i < 4; ++i) mrow4[i] = -1e30f;
#pragma unroll
      for (int cf = 0; cf < 4; ++cf)
#pragma unroll
        for (int i = 0; i < 4; ++i) {
          float v = sv[cf][i] * SCALE;
          sv[cf][i] = v;
          mrow4[i] = fmaxf(mrow4[i], ((mk >> (cf * 4 + i)) & 1u) ? v : -1e30f);
        }
#pragma unroll
      for (int d = 1; d <= 8; d <<= 1)
#pragma unroll
        for (int i = 0; i < 4; ++i)
          mrow4[i] = fmaxf(mrow4[i], __shfl_xor(mrow4[i], d, 64));

      float sf[4], lsum[4];
#pragma unroll
      for (int i = 0; i < 4; ++i) {
        float mn = fmaxf(mrun[qd][i], mrow4[i]);
        sf[i] = __expf(mrun[qd][i] - mn);
        mrun[qd][i] = mn;
        lsum[i] = 0.f;
      }
      f16* pslice = &p_lds[(w * 2 + qd) * 1152];
#pragma unroll
      for (int cf = 0; cf < 4; ++cf)
#pragma unroll
        for (int i = 0; i < 4; ++i) {
          float p = ((mk >> (cf * 4 + i)) & 1u) ? __expf(sv[cf][i] - mrun[qd][i]) : 0.f;
          lsum[i] += p;
          int row = g * 4 + i;
          int cchunk = 2 * cf + (lam >> 3);
          pslice[row * 72 + (((cchunk ^ (row & 7)) << 3) | (lam & 7))] = (f16)p;
        }
#pragma unroll
      for (int d = 1; d <= 8; d <<= 1)
#pragma unroll
        for (int i = 0; i < 4; ++i)
          lsum[i] += __shfl_xor(lsum[i], d, 64);
#pragma unroll
      for (int i = 0; i < 4; ++i) lrun[qd][i] = lrun[qd][i] * sf[i] + lsum[i];
#pragma unroll
      for (int nf = 0; nf < 8; ++nf)
#pragma unroll
        for (int i = 0; i < 4; ++i) acc[qd][nf][i] *= sf[i];
    }

    __builtin_amdgcn_s_setprio(1);
#pragma unroll
    for (int kc2 = 0; kc2 < 2; ++kc2) {
      f16x8 ap0 = *(const f16x8*)&p_lds[(w * 2 + 0) * 1152 + lam * 72 + (((4 * kc2 + g) ^ (lam & 7)) << 3)];
      f16x8 ap1 = *(const f16x8*)&p_lds[(w * 2 + 1) * 1152 + lam * 72 + (((4 * kc2 + g) ^ (lam & 7)) << 3)];
#pragma unroll
      for (int nf = 0; nf < 8; ++nf) {
        int vr = nf * 16 + lam;
        f16x8 bv = *(const f16x8*)&v_lds[vr * 64 + (((kc2 * 4 + g) ^ (vr & 7)) << 3)];
        acc[0][nf] = __builtin_amdgcn_mfma_f32_16x16x32_f16(ap0, bv, acc[0][nf], 0, 0, 0);
        acc[1][nf] = __builtin_amdgcn_mfma_f32_16x16x32_f16(ap1, bv, acc[1][nf], 0, 0, 0);
      }
    }
    __builtin_amdgcn_s_setprio(0);
  }

#pragma unroll
  for (int qd = 0; qd < 2; ++qd) {
    float inv[4];
#pragma unroll
    for (int i = 0; i < 4; ++i) inv[i] = (lrun[qd][i] > 0.f) ? 1.f / lrun[qd][i] : 0.f;
    const size_t orow0 = batch_row + (size_t)qt * 128 + w * 32 + qd * 16;
#pragma unroll
    for (int nf = 0; nf < 8; ++nf)
#pragma unroll
      for (int i = 0; i < 4; ++i)
        __builtin_nontemporal_store(acc[qd][nf][i] * inv[i],
            &outp[(orow0 + g * 4 + i) * 128 + nf * 16 + lam]);
  }
}

extern "C" void kernel_launch(void* const* d_in, const int* in_sizes, int n_in,
                              void* d_out, int out_size, void* d_ws, size_t ws_size,
                              hipStream_t stream) {
  const float* f1 = (const float*)d_in[0];
  const float* f2 = (const float*)d_in[1];
  const int* mask = (const int*)d_in[2];
  const float* W1 = (const float*)d_in[3];
  const float* b1 = (const float*)d_in[4];
  const float* W2 = (const float*)d_in[5];
  const float* b2 = (const float*)d_in[6];
  float* out = (float*)d_out;

  // ws: q_h(16MiB) k_h(16MiB) f1t(16MiB) bits(8MiB) = 56 MiB
  if (ws_size < (size_t)3 * 8388608 * sizeof(f16) + 8388608) return;

  f16* q_h = (f16*)d_ws;
  f16* k_h = q_h + 8388608;
  f16* f1t = k_h + 8388608;
  uint32_t* bits = (uint32_t*)(f1t + 8388608);
  // f2t lives in the out1 region of d_out: proj writes it; attn0 reads it;
  // attn1 overwrites that region afterwards (stream-ordered).
  f16* f2t = (f16*)d_out;

  proj_kernel<<<1024, 256, 0, stream>>>(f1, f2, W1, b1, W2, b2, q_h, k_h, f1t, f2t);
  // out layout: out1 [B,L2,F1] first, then out2 [B,L1,F2]
  attn0_kernel<<<1024, 256, 0, stream>>>(q_h, k_h, f2t, mask, bits, out + 8388608); // out2
  attn1_kernel<<<512, 256, 0, stream>>>(k_h, q_h, f1t, bits, out);                  // out1
}

// Round 19
// 240.731 us; speedup vs baseline: 1.0305x; 1.0305x over previous
//
#include <hip/hip_runtime.h>
#include <stdint.h>

typedef _Float16 f16;
typedef f16 f16x4 __attribute__((ext_vector_type(4)));
typedef f16 f16x8 __attribute__((ext_vector_type(8)));
typedef float f32x4 __attribute__((ext_vector_type(4)));

constexpr float SCALE = 0.08838834764831845f; // 1/sqrt(128)

__device__ __forceinline__ void glds16(const void* g, void* l) {
  __builtin_amdgcn_global_load_lds(
      (const __attribute__((address_space(1))) void*)g,
      (__attribute__((address_space(3))) void*)l, 16, 0, 0);
}
__device__ __forceinline__ void glds4(const void* g, void* l) {
  __builtin_amdgcn_global_load_lds(
      (const __attribute__((address_space(1))) void*)g,
      (__attribute__((address_space(3))) void*)l, 4, 0, 0);
}

// ---------------- projection (NT feature loads):
__global__ __launch_bounds__(256) void proj_kernel(
    const float* __restrict__ f1, const float* __restrict__ f2,
    const float* __restrict__ W1, const float* __restrict__ b1,
    const float* __restrict__ W2, const float* __restrict__ b2,
    f16* __restrict__ q_h, f16* __restrict__ k_h,
    f16* __restrict__ f1t, f16* __restrict__ f2t)
{
  __shared__ f16 a_lds[128 * 128];
  __shared__ f16 w_lds[128 * 128];

  const int tid = threadIdx.x;
  const int blk = blockIdx.x;
  const bool qside = blk < 512;
  const float* feat = qside ? f1 : f2;
  const float* W    = qside ? W1 : W2;
  const float* bias = qside ? b1 : b2;
  f16* op = qside ? q_h : k_h;
  f16* ft = qside ? f1t : f2t;
  const size_t row0 = (size_t)(qside ? blk : blk - 512) * 128;

  for (int it = 0; it < 16; ++it) {
    int u = tid + it * 256;
    int r = u >> 5;
    int c4 = (u & 31) * 4;
    f32x4 v = __builtin_nontemporal_load(
        (const f32x4*)&feat[(row0 + r) * 128 + c4]);
    f16x4 h4 = { (f16)v[0], (f16)v[1], (f16)v[2], (f16)v[3] };
    int adr = r * 128 + ((((c4 >> 3) ^ (r & 7)) << 3) | (c4 & 7));
    *(f16x4*)&a_lds[adr] = h4;
    float4 wv = *(const float4*)&W[r * 128 + c4];
    f16x4 wh = { (f16)wv.x, (f16)wv.y, (f16)wv.z, (f16)wv.w };
    *(f16x4*)&w_lds[adr] = wh;
  }
  __syncthreads();

  const int w = tid >> 6, l = tid & 63, lam = l & 15, g = l >> 4;
  f32x4 acc[2][8] = {};
#pragma unroll
  for (int kc = 0; kc < 4; ++kc) {
    f16x8 a[2];
#pragma unroll
    for (int rf = 0; rf < 2; ++rf) {
      int ar = w * 32 + rf * 16 + lam;
      a[rf] = *(const f16x8*)&a_lds[ar * 128 + (((4 * kc + g) ^ (ar & 7)) << 3)];
    }
#pragma unroll
    for (int cf = 0; cf < 8; ++cf) {
      int br = cf * 16 + lam;
      f16x8 bfr = *(const f16x8*)&w_lds[br * 128 + (((4 * kc + g) ^ (br & 7)) << 3)];
      acc[0][cf] = __builtin_amdgcn_mfma_f32_16x16x32_f16(a[0], bfr, acc[0][cf], 0, 0, 0);
      acc[1][cf] = __builtin_amdgcn_mfma_f32_16x16x32_f16(a[1], bfr, acc[1][cf], 0, 0, 0);
    }
  }
#pragma unroll
  for (int cf = 0; cf < 8; ++cf) {
    int col = cf * 16 + lam;
    float bv = bias[col];
#pragma unroll
    for (int rf = 0; rf < 2; ++rf)
#pragma unroll
      for (int i = 0; i < 4; ++i) {
        size_t grow = row0 + w * 32 + rf * 16 + g * 4 + i;
        op[grow * 128 + col] = (f16)(acc[rf][cf][i] + bv);
      }
  }

  { // transposed feature write: ft[b][f][l]
    const int b = (int)(row0 >> 10);
    const int l0 = (int)(row0 & 1023);
    const int f = tid >> 1;
    const int half = tid & 1;
    f16 buf[64];
#pragma unroll
    for (int j = 0; j < 64; ++j) {
      int r = half * 64 + j;
      buf[j] = a_lds[r * 128 + ((((f >> 3) ^ (r & 7)) << 3) | (f & 7))];
    }
    f16* dst = ft + ((size_t)b * 128 + f) * 1024 + l0 + half * 64;
#pragma unroll
    for (int c = 0; c < 8; ++c)
      *(f16x8*)&dst[c * 8] = *(const f16x8*)&buf[c * 8];
  }
}

// ---------------- attn PASS 0, QBLK=64, grid 1024 (r17/18-verified body).
// Counted-vmcnt mask pipeline (r18). NEW: mk dumped raw via 1 shfl + 1 store:
//   dump[((b*16+qt)*16+kt)*128 + (tid>>1)] = mk(even) | mk(odd)<<16
__global__ __launch_bounds__(256, 2) void attn0_kernel(
    const f16* __restrict__ Qh, const f16* __restrict__ Kh,
    const f16* __restrict__ Vt, const int* __restrict__ mask,
    uint32_t* __restrict__ dump, float* __restrict__ outp)
{
  __shared__ f16 k_lds[64 * 128];   // 16 KB
  __shared__ f16 v_lds[128 * 64];   // 16 KB
  __shared__ f16 p_lds[4 * 16 * 72];// 9 KB
  __shared__ int m_lds[2][64 * 64]; // 32 KB raw mask tiles

  const int tid = threadIdx.x;
  const int u = blockIdx.x;
  const int qt = (u >> 3) & 15;
  const int b = ((u >> 7) << 3) | (u & 7);
  const int w = tid >> 6, l = tid & 63, lam = l & 15, g = l >> 4;
  const size_t batch_row = (size_t)b << 10;
  const f16* vtb = Vt + ((size_t)b << 17);

  f16x8 qf[4];
  {
    const f16* qbase = Qh + (batch_row + qt * 64 + w * 16 + lam) * 128;
#pragma unroll
    for (int kc = 0; kc < 4; ++kc) qf[kc] = *(const f16x8*)&qbase[kc * 32 + g * 8];
  }

  auto stageMask = [&](int kt_, int bu) {
#pragma unroll
    for (int it = 0; it < 4; ++it) {
      int slot0 = (w * 4 + it) * 64;
      int i = slot0 + l;
      int r = i >> 4, cd = i & 15;
      int cg = cd ^ (r & 7);
      glds16(mask + (batch_row + qt * 64 + r) * 1024 + kt_ * 64 + cg * 4,
             &m_lds[bu][slot0 * 4]);
    }
  };

  f32x4 acc[8] = {};
  float mrun[4], lrun[4];
#pragma unroll
  for (int i = 0; i < 4; ++i) { mrun[i] = -__builtin_inff(); lrun[i] = 0.f; }

  stageMask(0, 0); // prologue: tile-0 mask in flight

  int c = 0;
  for (int kt = 0; kt < 16; ++kt) {
    const int kb = kt * 64;
    __builtin_amdgcn_s_barrier(); // barrier1: exec-only

    { // stage K tile
      const f16* kbase = Kh + (batch_row + kb) * 128;
#pragma unroll
      for (int it = 0; it < 4; ++it) {
        int slot0 = (w * 4 + it) * 64;
        int i = slot0 + l;
        int r = i >> 4, ch = i & 15;
        glds16(kbase + r * 128 + ((ch ^ (r & 7)) << 3), &k_lds[slot0 * 8]);
      }
    }
    { // stage V^T tile
#pragma unroll
      for (int it = 0; it < 4; ++it) {
        int slot0 = (w * 4 + it) * 64;
        int i = slot0 + l;
        int r = i >> 3, ch = i & 7;
        glds16(vtb + r * 1024 + kb + ((ch ^ (r & 7)) << 3), &v_lds[slot0 * 8]);
      }
    }
    // issue next mask tile BEFORE barrier2 (kt==15: dummy, never read)
    stageMask(kt < 15 ? kt + 1 : 15, c ^ 1);

    // barrier2: drain store(kt-1)+KV(kt)+mask(kt), leave mask(kt+1) flying
    asm volatile("s_waitcnt vmcnt(4)" ::: "memory");
    __builtin_amdgcn_s_barrier();

    // QK^T
    f32x4 sv[4] = {};
    __builtin_amdgcn_s_setprio(1);
#pragma unroll
    for (int kc = 0; kc < 4; ++kc) {
#pragma unroll
      for (int cf = 0; cf < 4; ++cf) {
        int br = cf * 16 + lam;
        f16x8 bk = *(const f16x8*)&k_lds[br * 128 + (((4 * kc + g) ^ (br & 7)) << 3)];
        sv[cf] = __builtin_amdgcn_mfma_f32_16x16x32_f16(qf[kc], bk, sv[cf], 0, 0, 0);
      }
    }
    __builtin_amdgcn_s_setprio(0);

    // gather mask from raw int tile (swizzled read)
    uint32_t mk = 0;
#pragma unroll
    for (int cf = 0; cf < 4; ++cf)
#pragma unroll
      for (int ii = 0; ii < 4; ++ii) {
        int rt = w * 16 + g * 4 + ii;
        int cc = cf * 16 + lam;
        int mv = m_lds[c][rt * 64 + (cc ^ ((rt & 7) << 2))];
        mk |= (mv != 0 ? 1u : 0u) << (cf * 4 + ii);
      }

    // dump raw mk pairs for pass 1 (1 shfl + 1 store per 2 threads)
    {
      uint32_t other = (uint32_t)__shfl_xor((int)mk, 1);
      if (!(l & 1))
        dump[(((size_t)b * 16 + qt) * 16 + kt) * 128 + (tid >> 1)] =
            (mk & 0xFFFFu) | (other << 16);
    }

    // online softmax over kv cols
    float mrow4[4];
#pragma unroll
    for (int i = 0; i < 4; ++i) mrow4[i] = -1e30f;
#pragma unroll
    for (int cf = 0; cf < 4; ++cf)
#pragma unroll
      for (int i = 0; i < 4; ++i) {
        float v = sv[cf][i] * SCALE;
        sv[cf][i] = v;
        mrow4[i] = fmaxf(mrow4[i], ((mk >> (cf * 4 + i)) & 1u) ? v : -1e30f);
      }
#pragma unroll
    for (int d = 1; d <= 8; d <<= 1)
#pragma unroll
      for (int i = 0; i < 4; ++i)
        mrow4[i] = fmaxf(mrow4[i], __shfl_xor(mrow4[i], d, 64));

    float sf[4], lsum[4];
#pragma unroll
    for (int i = 0; i < 4; ++i) {
      float mn = fmaxf(mrun[i], mrow4[i]);
      sf[i] = __expf(mrun[i] - mn);
      mrun[i] = mn;
      lsum[i] = 0.f;
    }
    f16* pslice = &p_lds[w * 1152];
#pragma unroll
    for (int cf = 0; cf < 4; ++cf)
#pragma unroll
      for (int i = 0; i < 4; ++i) {
        float p = ((mk >> (cf * 4 + i)) & 1u) ? __expf(sv[cf][i] - mrun[i]) : 0.f;
        lsum[i] += p;
        int row = g * 4 + i;
        int cchunk = 2 * cf + (lam >> 3);
        pslice[row * 72 + (((cchunk ^ (row & 7)) << 3) | (lam & 7))] = (f16)p;
      }
#pragma unroll
    for (int d = 1; d <= 8; d <<= 1)
#pragma unroll
      for (int i = 0; i < 4; ++i)
        lsum[i] += __shfl_xor(lsum[i], d, 64);
#pragma unroll
    for (int i = 0; i < 4; ++i) lrun[i] = lrun[i] * sf[i] + lsum[i];
#pragma unroll
    for (int nf = 0; nf < 8; ++nf)
#pragma unroll
      for (int i = 0; i < 4; ++i) acc[nf][i] *= sf[i];

    // PV
    __builtin_amdgcn_s_setprio(1);
#pragma unroll
    for (int kc2 = 0; kc2 < 2; ++kc2) {
      f16x8 ap = *(const f16x8*)&pslice[lam * 72 + (((4 * kc2 + g) ^ (lam & 7)) << 3)];
#pragma unroll
      for (int nf = 0; nf < 8; ++nf) {
        int vr = nf * 16 + lam;
        f16x8 bv = *(const f16x8*)&v_lds[vr * 64 + (((kc2 * 4 + g) ^ (vr & 7)) << 3)];
        acc[nf] = __builtin_amdgcn_mfma_f32_16x16x32_f16(ap, bv, acc[nf], 0, 0, 0);
      }
    }
    __builtin_amdgcn_s_setprio(0);
    c ^= 1;
  }

  float inv[4];
#pragma unroll
  for (int i = 0; i < 4; ++i) inv[i] = (lrun[i] > 0.f) ? 1.f / lrun[i] : 0.f;
  const size_t orow0 = batch_row + (size_t)qt * 64 + w * 16;
#pragma unroll
  for (int nf = 0; nf < 8; ++nf)
#pragma unroll
    for (int i = 0; i < 4; ++i)
      __builtin_nontemporal_store(acc[nf][i] * inv[i],
          &outp[(orow0 + g * 4 + i) * 128 + nf * 16 + lam]);
}

// ---------------- attn PASS 1, QBLK=128, grid 512. Consumes the mk-dump:
// for tile (qt1,kt1): words dump[b][kt1][qt1*2+h][0..128), h=w>>1 half.
// mask bit for (qrow = qt1*128+w*32+qd*16+g*4+i, kv = kt1*64+cf*16+lam):
//   j = cf*32 + (lam>>2)*8 + g*2 + (i>>1)
//   bit = 16*(i&1) + ((w&1)*2+qd)*4 + (lam&3)
__global__ __launch_bounds__(256, 2) void attn1_kernel(
    const f16* __restrict__ Qh, const f16* __restrict__ Kh,
    const f16* __restrict__ Vt, const uint32_t* __restrict__ dump,
    float* __restrict__ outp)
{
  __shared__ f16 k_lds[64 * 128];
  __shared__ f16 v_lds[128 * 64];
  __shared__ f16 p_lds[8 * 16 * 72];
  __shared__ uint32_t mb[256];          // [h][128]

  const int tid = threadIdx.x;
  const int u = blockIdx.x;
  const int qt = (u >> 3) & 7;
  const int b = ((u >> 6) << 3) | (u & 7);
  const int w = tid >> 6, l = tid & 63, lam = l & 15, g = l >> 4;
  const size_t batch_row = (size_t)b << 10;

  f16x8 qf[2][4];
#pragma unroll
  for (int qd = 0; qd < 2; ++qd) {
    const f16* qbase = Qh + (batch_row + qt * 128 + w * 32 + qd * 16 + lam) * 128;
#pragma unroll
    for (int kc = 0; kc < 4; ++kc) qf[qd][kc] = *(const f16x8*)&qbase[kc * 32 + g * 8];
  }

  f32x4 acc[2][8] = {};
  float mrun[2][4], lrun[2][4];
#pragma unroll
  for (int qd = 0; qd < 2; ++qd)
#pragma unroll
    for (int i = 0; i < 4; ++i) { mrun[qd][i] = -__builtin_inff(); lrun[qd][i] = 0.f; }

  const f16* vtb = Vt + ((size_t)b << 17);

  for (int kt = 0; kt < 16; ++kt) {
    const int kb = kt * 64;
    __syncthreads();
    {
      const f16* kbase = Kh + (batch_row + kb) * 128;
#pragma unroll
      for (int it = 0; it < 4; ++it) {
        int slot0 = (w * 4 + it) * 64;
        int i = slot0 + l;
        int r = i >> 4, ch = i & 15;
        glds16(kbase + r * 128 + ((ch ^ (r & 7)) << 3), &k_lds[slot0 * 8]);
      }
    }
    {
#pragma unroll
      for (int it = 0; it < 4; ++it) {
        int slot0 = (w * 4 + it) * 64;
        int i = slot0 + l;
        int r = i >> 3, ch = i & 7;
        glds16(vtb + r * 1024 + kb + ((ch ^ (r & 7)) << 3), &v_lds[slot0 * 8]);
      }
    }
    { // stage mk-dump words: [h=tid>>7][j=tid&127], coalesced, lane-linear
      glds4(dump + ((((size_t)b * 16 + kt) * 16) + qt * 2 + (tid >> 7)) * 128 + (tid & 127),
            &mb[w * 64]);
    }
    __syncthreads();

#pragma unroll
    for (int qd = 0; qd < 2; ++qd) {
      f32x4 sv[4] = {};
      __builtin_amdgcn_s_setprio(1);
#pragma unroll
      for (int kc = 0; kc < 4; ++kc) {
#pragma unroll
        for (int cf = 0; cf < 4; ++cf) {
          int br = cf * 16 + lam;
          f16x8 bk = *(const f16x8*)&k_lds[br * 128 + (((4 * kc + g) ^ (br & 7)) << 3)];
          sv[cf] = __builtin_amdgcn_mfma_f32_16x16x32_f16(qf[qd][kc], bk, sv[cf], 0, 0, 0);
        }
      }
      __builtin_amdgcn_s_setprio(0);

      // gather from mk-dump
      uint32_t mk = 0;
      const int bit0 = ((w & 1) * 2 + qd) * 4 + (lam & 3);
#pragma unroll
      for (int cf = 0; cf < 4; ++cf) {
        int j = cf * 32 + (lam >> 2) * 8 + g * 2;
        uint32_t w0 = mb[(w >> 1) * 128 + j];
        uint32_t w1 = mb[(w >> 1) * 128 + j + 1];
        mk |= ((w0 >> bit0) & 1u) << (cf * 4 + 0);
        mk |= ((w0 >> (16 + bit0)) & 1u) << (cf * 4 + 1);
        mk |= ((w1 >> bit0) & 1u) << (cf * 4 + 2);
        mk |= ((w1 >> (16 + bit0)) & 1u) << (cf * 4 + 3);
      }

      float mrow4[4];
#pragma unroll
      for (int i = 0; i < 4; ++i) mrow4[i] = -1e30f;
#pragma unroll
      for (int cf = 0; cf < 4; ++cf)
#pragma unroll
        for (int i = 0; i < 4; ++i) {
          float v = sv[cf][i] * SCALE;
          sv[cf][i] = v;
          mrow4[i] = fmaxf(mrow4[i], ((mk >> (cf * 4 + i)) & 1u) ? v : -1e30f);
        }
#pragma unroll
      for (int d = 1; d <= 8; d <<= 1)
#pragma unroll
        for (int i = 0; i < 4; ++i)
          mrow4[i] = fmaxf(mrow4[i], __shfl_xor(mrow4[i], d, 64));

      float sf[4], lsum[4];
#pragma unroll
      for (int i = 0; i < 4; ++i) {
        float mn = fmaxf(mrun[qd][i], mrow4[i]);
        sf[i] = __expf(mrun[qd][i] - mn);
        mrun[qd][i] = mn;
        lsum[i] = 0.f;
      }
      f16* pslice = &p_lds[(w * 2 + qd) * 1152];
#pragma unroll
      for (int cf = 0; cf < 4; ++cf)
#pragma unroll
        for (int i = 0; i < 4; ++i) {
          float p = ((mk >> (cf * 4 + i)) & 1u) ? __expf(sv[cf][i] - mrun[qd][i]) : 0.f;
          lsum[i] += p;
          int row = g * 4 + i;
          int cchunk = 2 * cf + (lam >> 3);
          pslice[row * 72 + (((cchunk ^ (row & 7)) << 3) | (lam & 7))] = (f16)p;
        }
#pragma unroll
      for (int d = 1; d <= 8; d <<= 1)
#pragma unroll
        for (int i = 0; i < 4; ++i)
          lsum[i] += __shfl_xor(lsum[i], d, 64);
#pragma unroll
      for (int i = 0; i < 4; ++i) lrun[qd][i] = lrun[qd][i] * sf[i] + lsum[i];
#pragma unroll
      for (int nf = 0; nf < 8; ++nf)
#pragma unroll
        for (int i = 0; i < 4; ++i) acc[qd][nf][i] *= sf[i];
    }

    __builtin_amdgcn_s_setprio(1);
#pragma unroll
    for (int kc2 = 0; kc2 < 2; ++kc2) {
      f16x8 ap0 = *(const f16x8*)&p_lds[(w * 2 + 0) * 1152 + lam * 72 + (((4 * kc2 + g) ^ (lam & 7)) << 3)];
      f16x8 ap1 = *(const f16x8*)&p_lds[(w * 2 + 1) * 1152 + lam * 72 + (((4 * kc2 + g) ^ (lam & 7)) << 3)];
#pragma unroll
      for (int nf = 0; nf < 8; ++nf) {
        int vr = nf * 16 + lam;
        f16x8 bv = *(const f16x8*)&v_lds[vr * 64 + (((kc2 * 4 + g) ^ (vr & 7)) << 3)];
        acc[0][nf] = __builtin_amdgcn_mfma_f32_16x16x32_f16(ap0, bv, acc[0][nf], 0, 0, 0);
        acc[1][nf] = __builtin_amdgcn_mfma_f32_16x16x32_f16(ap1, bv, acc[1][nf], 0, 0, 0);
      }
    }
    __builtin_amdgcn_s_setprio(0);
  }

#pragma unroll
  for (int qd = 0; qd < 2; ++qd) {
    float inv[4];
#pragma unroll
    for (int i = 0; i < 4; ++i) inv[i] = (lrun[qd][i] > 0.f) ? 1.f / lrun[qd][i] : 0.f;
    const size_t orow0 = batch_row + (size_t)qt * 128 + w * 32 + qd * 16;
#pragma unroll
    for (int nf = 0; nf < 8; ++nf)
#pragma unroll
      for (int i = 0; i < 4; ++i)
        __builtin_nontemporal_store(acc[qd][nf][i] * inv[i],
            &outp[(orow0 + g * 4 + i) * 128 + nf * 16 + lam]);
  }
}

extern "C" void kernel_launch(void* const* d_in, const int* in_sizes, int n_in,
                              void* d_out, int out_size, void* d_ws, size_t ws_size,
                              hipStream_t stream) {
  const float* f1 = (const float*)d_in[0];
  const float* f2 = (const float*)d_in[1];
  const int* mask = (const int*)d_in[2];
  const float* W1 = (const float*)d_in[3];
  const float* b1 = (const float*)d_in[4];
  const float* W2 = (const float*)d_in[5];
  const float* b2 = (const float*)d_in[6];
  float* out = (float*)d_out;

  // ws: q_h(16MiB) k_h(16MiB) f1t(16MiB) dump(8MiB) = 56 MiB
  if (ws_size < (size_t)3 * 8388608 * sizeof(f16) + 8388608) return;

  f16* q_h = (f16*)d_ws;
  f16* k_h = q_h + 8388608;
  f16* f1t = k_h + 8388608;
  uint32_t* dump = (uint32_t*)(f1t + 8388608);
  // f2t lives in the out1 region of d_out: proj writes it; attn0 reads it;
  // attn1 overwrites that region afterwards (stream-ordered).
  f16* f2t = (f16*)d_out;

  proj_kernel<<<1024, 256, 0, stream>>>(f1, f2, W1, b1, W2, b2, q_h, k_h, f1t, f2t);
  // out layout: out1 [B,L2,F1] first, then out2 [B,L1,F2]
  attn0_kernel<<<1024, 256, 0, stream>>>(q_h, k_h, f2t, mask, dump, out + 8388608); // out2
  attn1_kernel<<<512, 256, 0, stream>>>(k_h, q_h, f1t, dump, out);                  // out1
}

// Round 20
// 222.514 us; speedup vs baseline: 1.1149x; 1.0819x over previous
//
#include <hip/hip_runtime.h>
#include <stdint.h>

typedef _Float16 f16;
typedef f16 f16x4 __attribute__((ext_vector_type(4)));
typedef f16 f16x8 __attribute__((ext_vector_type(8)));
typedef float f32x4 __attribute__((ext_vector_type(4)));

constexpr float SCALE2 = 0.08838834764831845f * 1.44269504088896f; // 1/sqrt(128) * log2(e)

__device__ __forceinline__ void glds16(const void* g, void* l) {
  __builtin_amdgcn_global_load_lds(
      (const __attribute__((address_space(1))) void*)g,
      (__attribute__((address_space(3))) void*)l, 16, 0, 0);
}
__device__ __forceinline__ void glds4(const void* g, void* l) {
  __builtin_amdgcn_global_load_lds(
      (const __attribute__((address_space(1))) void*)g,
      (__attribute__((address_space(3))) void*)l, 4, 0, 0);
}

// ---------------- projection (NT feature loads):
__global__ __launch_bounds__(256) void proj_kernel(
    const float* __restrict__ f1, const float* __restrict__ f2,
    const float* __restrict__ W1, const float* __restrict__ b1,
    const float* __restrict__ W2, const float* __restrict__ b2,
    f16* __restrict__ q_h, f16* __restrict__ k_h,
    f16* __restrict__ f1t, f16* __restrict__ f2t)
{
  __shared__ f16 a_lds[128 * 128];
  __shared__ f16 w_lds[128 * 128];

  const int tid = threadIdx.x;
  const int blk = blockIdx.x;
  const bool qside = blk < 512;
  const float* feat = qside ? f1 : f2;
  const float* W    = qside ? W1 : W2;
  const float* bias = qside ? b1 : b2;
  f16* op = qside ? q_h : k_h;
  f16* ft = qside ? f1t : f2t;
  const size_t row0 = (size_t)(qside ? blk : blk - 512) * 128;

  for (int it = 0; it < 16; ++it) {
    int u = tid + it * 256;
    int r = u >> 5;
    int c4 = (u & 31) * 4;
    f32x4 v = __builtin_nontemporal_load(
        (const f32x4*)&feat[(row0 + r) * 128 + c4]);
    f16x4 h4 = { (f16)v[0], (f16)v[1], (f16)v[2], (f16)v[3] };
    int adr = r * 128 + ((((c4 >> 3) ^ (r & 7)) << 3) | (c4 & 7));
    *(f16x4*)&a_lds[adr] = h4;
    float4 wv = *(const float4*)&W[r * 128 + c4];
    f16x4 wh = { (f16)wv.x, (f16)wv.y, (f16)wv.z, (f16)wv.w };
    *(f16x4*)&w_lds[adr] = wh;
  }
  __syncthreads();

  const int w = tid >> 6, l = tid & 63, lam = l & 15, g = l >> 4;
  f32x4 acc[2][8] = {};
#pragma unroll
  for (int kc = 0; kc < 4; ++kc) {
    f16x8 a[2];
#pragma unroll
    for (int rf = 0; rf < 2; ++rf) {
      int ar = w * 32 + rf * 16 + lam;
      a[rf] = *(const f16x8*)&a_lds[ar * 128 + (((4 * kc + g) ^ (ar & 7)) << 3)];
    }
#pragma unroll
    for (int cf = 0; cf < 8; ++cf) {
      int br = cf * 16 + lam;
      f16x8 bfr = *(const f16x8*)&w_lds[br * 128 + (((4 * kc + g) ^ (br & 7)) << 3)];
      acc[0][cf] = __builtin_amdgcn_mfma_f32_16x16x32_f16(a[0], bfr, acc[0][cf], 0, 0, 0);
      acc[1][cf] = __builtin_amdgcn_mfma_f32_16x16x32_f16(a[1], bfr, acc[1][cf], 0, 0, 0);
    }
  }
#pragma unroll
  for (int cf = 0; cf < 8; ++cf) {
    int col = cf * 16 + lam;
    float bv = bias[col];
#pragma unroll
    for (int rf = 0; rf < 2; ++rf)
#pragma unroll
      for (int i = 0; i < 4; ++i) {
        size_t grow = row0 + w * 32 + rf * 16 + g * 4 + i;
        op[grow * 128 + col] = (f16)(acc[rf][cf][i] + bv);
      }
  }

  { // transposed feature write: ft[b][f][l]
    const int b = (int)(row0 >> 10);
    const int l0 = (int)(row0 & 1023);
    const int f = tid >> 1;
    const int half = tid & 1;
    f16 buf[64];
#pragma unroll
    for (int j = 0; j < 64; ++j) {
      int r = half * 64 + j;
      buf[j] = a_lds[r * 128 + ((((f >> 3) ^ (r & 7)) << 3) | (f & 7))];
    }
    f16* dst = ft + ((size_t)b * 128 + f) * 1024 + l0 + half * 64;
#pragma unroll
    for (int c = 0; c < 8; ++c)
      *(f16x8*)&dst[c * 8] = *(const f16x8*)&buf[c * 8];
  }
}

// ---------------- attn PASS 0, QBLK=64, grid 1024 (r18/19-verified body).
// Counted-vmcnt mask pipeline; exp2 softmax; deferred lsum reduce;
// dump store moved after PV (off critical path), NT.
__global__ __launch_bounds__(256, 2) void attn0_kernel(
    const f16* __restrict__ Qh, const f16* __restrict__ Kh,
    const f16* __restrict__ Vt, const int* __restrict__ mask,
    uint32_t* __restrict__ dump, float* __restrict__ outp)
{
  __shared__ f16 k_lds[64 * 128];   // 16 KB
  __shared__ f16 v_lds[128 * 64];   // 16 KB
  __shared__ f16 p_lds[4 * 16 * 72];// 9 KB
  __shared__ int m_lds[2][64 * 64]; // 32 KB raw mask tiles

  const int tid = threadIdx.x;
  const int u = blockIdx.x;
  const int qt = (u >> 3) & 15;
  const int b = ((u >> 7) << 3) | (u & 7);
  const int w = tid >> 6, l = tid & 63, lam = l & 15, g = l >> 4;
  const size_t batch_row = (size_t)b << 10;
  const f16* vtb = Vt + ((size_t)b << 17);

  f16x8 qf[4];
  {
    const f16* qbase = Qh + (batch_row + qt * 64 + w * 16 + lam) * 128;
#pragma unroll
    for (int kc = 0; kc < 4; ++kc) qf[kc] = *(const f16x8*)&qbase[kc * 32 + g * 8];
  }

  auto stageMask = [&](int kt_, int bu) {
#pragma unroll
    for (int it = 0; it < 4; ++it) {
      int slot0 = (w * 4 + it) * 64;
      int i = slot0 + l;
      int r = i >> 4, cd = i & 15;
      int cg = cd ^ (r & 7);
      glds16(mask + (batch_row + qt * 64 + r) * 1024 + kt_ * 64 + cg * 4,
             &m_lds[bu][slot0 * 4]);
    }
  };

  f32x4 acc[8] = {};
  float mrun[4], lrun[4];
#pragma unroll
  for (int i = 0; i < 4; ++i) { mrun[i] = -1e30f; lrun[i] = 0.f; }

  stageMask(0, 0); // prologue: tile-0 mask in flight

  int c = 0;
  for (int kt = 0; kt < 16; ++kt) {
    const int kb = kt * 64;
    __builtin_amdgcn_s_barrier(); // barrier1: exec-only

    { // stage K tile
      const f16* kbase = Kh + (batch_row + kb) * 128;
#pragma unroll
      for (int it = 0; it < 4; ++it) {
        int slot0 = (w * 4 + it) * 64;
        int i = slot0 + l;
        int r = i >> 4, ch = i & 15;
        glds16(kbase + r * 128 + ((ch ^ (r & 7)) << 3), &k_lds[slot0 * 8]);
      }
    }
    { // stage V^T tile
#pragma unroll
      for (int it = 0; it < 4; ++it) {
        int slot0 = (w * 4 + it) * 64;
        int i = slot0 + l;
        int r = i >> 3, ch = i & 7;
        glds16(vtb + r * 1024 + kb + ((ch ^ (r & 7)) << 3), &v_lds[slot0 * 8]);
      }
    }
    // issue next mask tile BEFORE barrier2 (kt==15: dummy, never read)
    stageMask(kt < 15 ? kt + 1 : 15, c ^ 1);

    // barrier2: drain store(kt-1)+KV(kt)+mask(kt), leave mask(kt+1) flying
    asm volatile("s_waitcnt vmcnt(4)" ::: "memory");
    __builtin_amdgcn_s_barrier();

    // QK^T
    f32x4 sv[4] = {};
    __builtin_amdgcn_s_setprio(1);
#pragma unroll
    for (int kc = 0; kc < 4; ++kc) {
#pragma unroll
      for (int cf = 0; cf < 4; ++cf) {
        int br = cf * 16 + lam;
        f16x8 bk = *(const f16x8*)&k_lds[br * 128 + (((4 * kc + g) ^ (br & 7)) << 3)];
        sv[cf] = __builtin_amdgcn_mfma_f32_16x16x32_f16(qf[kc], bk, sv[cf], 0, 0, 0);
      }
    }
    __builtin_amdgcn_s_setprio(0);

    // gather mask from raw int tile (swizzled read)
    uint32_t mk = 0;
#pragma unroll
    for (int cf = 0; cf < 4; ++cf)
#pragma unroll
      for (int ii = 0; ii < 4; ++ii) {
        int rt = w * 16 + g * 4 + ii;
        int cc = cf * 16 + lam;
        int mv = m_lds[c][rt * 64 + (cc ^ ((rt & 7) << 2))];
        mk |= (mv != 0 ? 1u : 0u) << (cf * 4 + ii);
      }

    // online softmax over kv cols (log2 space; lsum reduce deferred)
    float mrow4[4];
#pragma unroll
    for (int i = 0; i < 4; ++i) mrow4[i] = -1e30f;
#pragma unroll
    for (int cf = 0; cf < 4; ++cf)
#pragma unroll
      for (int i = 0; i < 4; ++i) {
        float v = sv[cf][i] * SCALE2;
        sv[cf][i] = v;
        mrow4[i] = fmaxf(mrow4[i], ((mk >> (cf * 4 + i)) & 1u) ? v : -1e30f);
      }
#pragma unroll
    for (int d = 1; d <= 8; d <<= 1)
#pragma unroll
      for (int i = 0; i < 4; ++i)
        mrow4[i] = fmaxf(mrow4[i], __shfl_xor(mrow4[i], d, 64));

    float sf[4], lsum[4];
#pragma unroll
    for (int i = 0; i < 4; ++i) {
      float mn = fmaxf(mrun[i], mrow4[i]);
      sf[i] = __builtin_amdgcn_exp2f(mrun[i] - mn);
      mrun[i] = mn;
      lsum[i] = 0.f;
    }
    f16* pslice = &p_lds[w * 1152];
#pragma unroll
    for (int cf = 0; cf < 4; ++cf)
#pragma unroll
      for (int i = 0; i < 4; ++i) {
        float p = ((mk >> (cf * 4 + i)) & 1u)
                      ? __builtin_amdgcn_exp2f(sv[cf][i] - mrun[i]) : 0.f;
        lsum[i] += p;
        int row = g * 4 + i;
        int cchunk = 2 * cf + (lam >> 3);
        pslice[row * 72 + (((cchunk ^ (row & 7)) << 3) | (lam & 7))] = (f16)p;
      }
#pragma unroll
    for (int i = 0; i < 4; ++i) lrun[i] = lrun[i] * sf[i] + lsum[i]; // per-lane partial
#pragma unroll
    for (int nf = 0; nf < 8; ++nf)
#pragma unroll
      for (int i = 0; i < 4; ++i) acc[nf][i] *= sf[i];

    // PV
    __builtin_amdgcn_s_setprio(1);
#pragma unroll
    for (int kc2 = 0; kc2 < 2; ++kc2) {
      f16x8 ap = *(const f16x8*)&pslice[lam * 72 + (((4 * kc2 + g) ^ (lam & 7)) << 3)];
#pragma unroll
      for (int nf = 0; nf < 8; ++nf) {
        int vr = nf * 16 + lam;
        f16x8 bv = *(const f16x8*)&v_lds[vr * 64 + (((kc2 * 4 + g) ^ (vr & 7)) << 3)];
        acc[nf] = __builtin_amdgcn_mfma_f32_16x16x32_f16(ap, bv, acc[nf], 0, 0, 0);
      }
    }
    __builtin_amdgcn_s_setprio(0);

    // dump raw mk pairs for pass 1 (off critical path; NT store)
    {
      uint32_t other = (uint32_t)__shfl_xor((int)mk, 1);
      if (!(l & 1))
        __builtin_nontemporal_store(
            (mk & 0xFFFFu) | (other << 16),
            &dump[(((size_t)b * 16 + qt) * 16 + kt) * 128 + (tid >> 1)]);
    }
    c ^= 1;
  }

  // deferred lsum cross-lane reduce
#pragma unroll
  for (int d = 1; d <= 8; d <<= 1)
#pragma unroll
    for (int i = 0; i < 4; ++i)
      lrun[i] += __shfl_xor(lrun[i], d, 64);

  float inv[4];
#pragma unroll
  for (int i = 0; i < 4; ++i) inv[i] = (lrun[i] > 0.f) ? 1.f / lrun[i] : 0.f;
  const size_t orow0 = batch_row + (size_t)qt * 64 + w * 16;
#pragma unroll
  for (int nf = 0; nf < 8; ++nf)
#pragma unroll
    for (int i = 0; i < 4; ++i)
      __builtin_nontemporal_store(acc[nf][i] * inv[i],
          &outp[(orow0 + g * 4 + i) * 128 + nf * 16 + lam]);
}

// ---------------- attn PASS 1, QBLK=128, grid 512 (r19-verified gather;
// exp2 softmax; deferred lsum reduce)
__global__ __launch_bounds__(256, 2) void attn1_kernel(
    const f16* __restrict__ Qh, const f16* __restrict__ Kh,
    const f16* __restrict__ Vt, const uint32_t* __restrict__ dump,
    float* __restrict__ outp)
{
  __shared__ f16 k_lds[64 * 128];
  __shared__ f16 v_lds[128 * 64];
  __shared__ f16 p_lds[8 * 16 * 72];
  __shared__ uint32_t mb[256];          // [h][128]

  const int tid = threadIdx.x;
  const int u = blockIdx.x;
  const int qt = (u >> 3) & 7;
  const int b = ((u >> 6) << 3) | (u & 7);
  const int w = tid >> 6, l = tid & 63, lam = l & 15, g = l >> 4;
  const size_t batch_row = (size_t)b << 10;

  f16x8 qf[2][4];
#pragma unroll
  for (int qd = 0; qd < 2; ++qd) {
    const f16* qbase = Qh + (batch_row + qt * 128 + w * 32 + qd * 16 + lam) * 128;
#pragma unroll
    for (int kc = 0; kc < 4; ++kc) qf[qd][kc] = *(const f16x8*)&qbase[kc * 32 + g * 8];
  }

  f32x4 acc[2][8] = {};
  float mrun[2][4], lrun[2][4];
#pragma unroll
  for (int qd = 0; qd < 2; ++qd)
#pragma unroll
    for (int i = 0; i < 4; ++i) { mrun[qd][i] = -1e30f; lrun[qd][i] = 0.f; }

  const f16* vtb = Vt + ((size_t)b << 17);

  for (int kt = 0; kt < 16; ++kt) {
    const int kb = kt * 64;
    __syncthreads();
    {
      const f16* kbase = Kh + (batch_row + kb) * 128;
#pragma unroll
      for (int it = 0; it < 4; ++it) {
        int slot0 = (w * 4 + it) * 64;
        int i = slot0 + l;
        int r = i >> 4, ch = i & 15;
        glds16(kbase + r * 128 + ((ch ^ (r & 7)) << 3), &k_lds[slot0 * 8]);
      }
    }
    {
#pragma unroll
      for (int it = 0; it < 4; ++it) {
        int slot0 = (w * 4 + it) * 64;
        int i = slot0 + l;
        int r = i >> 3, ch = i & 7;
        glds16(vtb + r * 1024 + kb + ((ch ^ (r & 7)) << 3), &v_lds[slot0 * 8]);
      }
    }
    { // stage mk-dump words: coalesced, lane-linear
      glds4(dump + ((((size_t)b * 16 + kt) * 16) + qt * 2 + (tid >> 7)) * 128 + (tid & 127),
            &mb[w * 64]);
    }
    __syncthreads();

#pragma unroll
    for (int qd = 0; qd < 2; ++qd) {
      f32x4 sv[4] = {};
      __builtin_amdgcn_s_setprio(1);
#pragma unroll
      for (int kc = 0; kc < 4; ++kc) {
#pragma unroll
        for (int cf = 0; cf < 4; ++cf) {
          int br = cf * 16 + lam;
          f16x8 bk = *(const f16x8*)&k_lds[br * 128 + (((4 * kc + g) ^ (br & 7)) << 3)];
          sv[cf] = __builtin_amdgcn_mfma_f32_16x16x32_f16(qf[qd][kc], bk, sv[cf], 0, 0, 0);
        }
      }
      __builtin_amdgcn_s_setprio(0);

      // gather from mk-dump
      uint32_t mk = 0;
      const int bit0 = ((w & 1) * 2 + qd) * 4 + (lam & 3);
#pragma unroll
      for (int cf = 0; cf < 4; ++cf) {
        int j = cf * 32 + (lam >> 2) * 8 + g * 2;
        uint32_t w0 = mb[(w >> 1) * 128 + j];
        uint32_t w1 = mb[(w >> 1) * 128 + j + 1];
        mk |= ((w0 >> bit0) & 1u) << (cf * 4 + 0);
        mk |= ((w0 >> (16 + bit0)) & 1u) << (cf * 4 + 1);
        mk |= ((w1 >> bit0) & 1u) << (cf * 4 + 2);
        mk |= ((w1 >> (16 + bit0)) & 1u) << (cf * 4 + 3);
      }

      float mrow4[4];
#pragma unroll
      for (int i = 0; i < 4; ++i) mrow4[i] = -1e30f;
#pragma unroll
      for (int cf = 0; cf < 4; ++cf)
#pragma unroll
        for (int i = 0; i < 4; ++i) {
          float v = sv[cf][i] * SCALE2;
          sv[cf][i] = v;
          mrow4[i] = fmaxf(mrow4[i], ((mk >> (cf * 4 + i)) & 1u) ? v : -1e30f);
        }
#pragma unroll
      for (int d = 1; d <= 8; d <<= 1)
#pragma unroll
        for (int i = 0; i < 4; ++i)
          mrow4[i] = fmaxf(mrow4[i], __shfl_xor(mrow4[i], d, 64));

      float sf[4], lsum[4];
#pragma unroll
      for (int i = 0; i < 4; ++i) {
        float mn = fmaxf(mrun[qd][i], mrow4[i]);
        sf[i] = __builtin_amdgcn_exp2f(mrun[qd][i] - mn);
        mrun[qd][i] = mn;
        lsum[i] = 0.f;
      }
      f16* pslice = &p_lds[(w * 2 + qd) * 1152];
#pragma unroll
      for (int cf = 0; cf < 4; ++cf)
#pragma unroll
        for (int i = 0; i < 4; ++i) {
          float p = ((mk >> (cf * 4 + i)) & 1u)
                        ? __builtin_amdgcn_exp2f(sv[cf][i] - mrun[qd][i]) : 0.f;
          lsum[i] += p;
          int row = g * 4 + i;
          int cchunk = 2 * cf + (lam >> 3);
          pslice[row * 72 + (((cchunk ^ (row & 7)) << 3) | (lam & 7))] = (f16)p;
        }
#pragma unroll
      for (int i = 0; i < 4; ++i) lrun[qd][i] = lrun[qd][i] * sf[i] + lsum[i];
#pragma unroll
      for (int nf = 0; nf < 8; ++nf)
#pragma unroll
        for (int i = 0; i < 4; ++i) acc[qd][nf][i] *= sf[i];
    }

    __builtin_amdgcn_s_setprio(1);
#pragma unroll
    for (int kc2 = 0; kc2 < 2; ++kc2) {
      f16x8 ap0 = *(const f16x8*)&p_lds[(w * 2 + 0) * 1152 + lam * 72 + (((4 * kc2 + g) ^ (lam & 7)) << 3)];
      f16x8 ap1 = *(const f16x8*)&p_lds[(w * 2 + 1) * 1152 + lam * 72 + (((4 * kc2 + g) ^ (lam & 7)) << 3)];
#pragma unroll
      for (int nf = 0; nf < 8; ++nf) {
        int vr = nf * 16 + lam;
        f16x8 bv = *(const f16x8*)&v_lds[vr * 64 + (((kc2 * 4 + g) ^ (vr & 7)) << 3)];
        acc[0][nf] = __builtin_amdgcn_mfma_f32_16x16x32_f16(ap0, bv, acc[0][nf], 0, 0, 0);
        acc[1][nf] = __builtin_amdgcn_mfma_f32_16x16x32_f16(ap1, bv, acc[1][nf], 0, 0, 0);
      }
    }
    __builtin_amdgcn_s_setprio(0);
  }

#pragma unroll
  for (int qd = 0; qd < 2; ++qd) {
#pragma unroll
    for (int d = 1; d <= 8; d <<= 1)
#pragma unroll
      for (int i = 0; i < 4; ++i)
        lrun[qd][i] += __shfl_xor(lrun[qd][i], d, 64);
    float inv[4];
#pragma unroll
    for (int i = 0; i < 4; ++i) inv[i] = (lrun[qd][i] > 0.f) ? 1.f / lrun[qd][i] : 0.f;
    const size_t orow0 = batch_row + (size_t)qt * 128 + w * 32 + qd * 16;
#pragma unroll
    for (int nf = 0; nf < 8; ++nf)
#pragma unroll
      for (int i = 0; i < 4; ++i)
        __builtin_nontemporal_store(acc[qd][nf][i] * inv[i],
            &outp[(orow0 + g * 4 + i) * 128 + nf * 16 + lam]);
  }
}

extern "C" void kernel_launch(void* const* d_in, const int* in_sizes, int n_in,
                              void* d_out, int out_size, void* d_ws, size_t ws_size,
                              hipStream_t stream) {
  const float* f1 = (const float*)d_in[0];
  const float* f2 = (const float*)d_in[1];
  const int* mask = (const int*)d_in[2];
  const float* W1 = (const float*)d_in[3];
  const float* b1 = (const float*)d_in[4];
  const float* W2 = (const float*)d_in[5];
  const float* b2 = (const float*)d_in[6];
  float* out = (float*)d_out;

  // ws: q_h(16MiB) k_h(16MiB) f1t(16MiB) dump(8MiB) = 56 MiB
  if (ws_size < (size_t)3 * 8388608 * sizeof(f16) + 8388608) return;

  f16* q_h = (f16*)d_ws;
  f16* k_h = q_h + 8388608;
  f16* f1t = k_h + 8388608;
  uint32_t* dump = (uint32_t*)(f1t + 8388608);
  // f2t lives in the out1 region of d_out: proj writes it; attn0 reads it;
  // attn1 overwrites that region afterwards (stream-ordered).
  f16* f2t = (f16*)d_out;

  proj_kernel<<<1024, 256, 0, stream>>>(f1, f2, W1, b1, W2, b2, q_h, k_h, f1t, f2t);
  // out layout: out1 [B,L2,F1] first, then out2 [B,L1,F2]
  attn0_kernel<<<1024, 256, 0, stream>>>(q_h, k_h, f2t, mask, dump, out + 8388608); // out2
  attn1_kernel<<<512, 256, 0, stream>>>(k_h, q_h, f1t, dump, out);                  // out1
}

// Round 22
// 221.587 us; speedup vs baseline: 1.1195x; 1.0042x over previous
//
#include <hip/hip_runtime.h>
#include <stdint.h>

typedef _Float16 f16;
typedef f16 f16x4 __attribute__((ext_vector_type(4)));
typedef f16 f16x8 __attribute__((ext_vector_type(8)));
typedef float f32x4 __attribute__((ext_vector_type(4)));

constexpr float SCALE2 = 0.08838834764831845f * 1.44269504088896f; // 1/sqrt(128) * log2(e)

__device__ __forceinline__ void glds16(const void* g, void* l) {
  __builtin_amdgcn_global_load_lds(
      (const __attribute__((address_space(1))) void*)g,
      (__attribute__((address_space(3))) void*)l, 16, 0, 0);
}
__device__ __forceinline__ void glds4(const void* g, void* l) {
  __builtin_amdgcn_global_load_lds(
      (const __attribute__((address_space(1))) void*)g,
      (__attribute__((address_space(3))) void*)l, 4, 0, 0);
}

// ---------------- projection (NT feature loads; C-write via LDS restage):
__global__ __launch_bounds__(256) void proj_kernel(
    const float* __restrict__ f1, const float* __restrict__ f2,
    const float* __restrict__ W1, const float* __restrict__ b1,
    const float* __restrict__ W2, const float* __restrict__ b2,
    f16* __restrict__ q_h, f16* __restrict__ k_h,
    f16* __restrict__ f1t, f16* __restrict__ f2t)
{
  __shared__ f16 a_lds[128 * 128];
  __shared__ f16 w_lds[128 * 128];

  const int tid = threadIdx.x;
  const int blk = blockIdx.x;
  const bool qside = blk < 512;
  const float* feat = qside ? f1 : f2;
  const float* W    = qside ? W1 : W2;
  const float* bias = qside ? b1 : b2;
  f16* op = qside ? q_h : k_h;
  f16* ft = qside ? f1t : f2t;
  const size_t row0 = (size_t)(qside ? blk : blk - 512) * 128;

  for (int it = 0; it < 16; ++it) {
    int u = tid + it * 256;
    int r = u >> 5;
    int c4 = (u & 31) * 4;
    f32x4 v = __builtin_nontemporal_load(
        (const f32x4*)&feat[(row0 + r) * 128 + c4]);
    f16x4 h4 = { (f16)v[0], (f16)v[1], (f16)v[2], (f16)v[3] };
    int adr = r * 128 + ((((c4 >> 3) ^ (r & 7)) << 3) | (c4 & 7));
    *(f16x4*)&a_lds[adr] = h4;
    float4 wv = *(const float4*)&W[r * 128 + c4];
    f16x4 wh = { (f16)wv.x, (f16)wv.y, (f16)wv.z, (f16)wv.w };
    *(f16x4*)&w_lds[adr] = wh;
  }
  __syncthreads();

  const int w = tid >> 6, l = tid & 63, lam = l & 15, g = l >> 4;
  f32x4 acc[2][8] = {};
#pragma unroll
  for (int kc = 0; kc < 4; ++kc) {
    f16x8 a[2];
#pragma unroll
    for (int rf = 0; rf < 2; ++rf) {
      int ar = w * 32 + rf * 16 + lam;
      a[rf] = *(const f16x8*)&a_lds[ar * 128 + (((4 * kc + g) ^ (ar & 7)) << 3)];
    }
#pragma unroll
    for (int cf = 0; cf < 8; ++cf) {
      int br = cf * 16 + lam;
      f16x8 bfr = *(const f16x8*)&w_lds[br * 128 + (((4 * kc + g) ^ (br & 7)) << 3)];
      acc[0][cf] = __builtin_amdgcn_mfma_f32_16x16x32_f16(a[0], bfr, acc[0][cf], 0, 0, 0);
      acc[1][cf] = __builtin_amdgcn_mfma_f32_16x16x32_f16(a[1], bfr, acc[1][cf], 0, 0, 0);
    }
  }

  { // transposed feature write: ft[b][f][l] (reads a_lds only)
    const int b = (int)(row0 >> 10);
    const int l0 = (int)(row0 & 1023);
    const int f = tid >> 1;
    const int half = tid & 1;
    f16 buf[64];
#pragma unroll
    for (int j = 0; j < 64; ++j) {
      int r = half * 64 + j;
      buf[j] = a_lds[r * 128 + ((((f >> 3) ^ (r & 7)) << 3) | (f & 7))];
    }
    f16* dst = ft + ((size_t)b * 128 + f) * 1024 + l0 + half * 64;
#pragma unroll
    for (int c = 0; c < 8; ++c)
      *(f16x8*)&dst[c * 8] = *(const f16x8*)&buf[c * 8];
  }

  // --- C write via LDS restage: scalar swizzled writes -> coalesced 16B stores
  __syncthreads(); // all MFMA-phase w_lds reads complete
#pragma unroll
  for (int cf = 0; cf < 8; ++cf) {
    int col = cf * 16 + lam;
    float bv = bias[col];
#pragma unroll
    for (int rf = 0; rf < 2; ++rf)
#pragma unroll
      for (int i = 0; i < 4; ++i) {
        int row = w * 32 + rf * 16 + g * 4 + i;
        w_lds[row * 128 + ((((col >> 3) ^ (row & 7)) << 3) | (col & 7))] =
            (f16)(acc[rf][cf][i] + bv);
      }
  }
  __syncthreads();
#pragma unroll
  for (int it = 0; it < 8; ++it) { // 128 rows x 16 chunks / 256 threads = 8
    int u = tid + it * 256;
    int r = u >> 4, c8 = (u & 15) * 8;
    f16x8 vv = *(const f16x8*)&w_lds[r * 128 + ((((c8 >> 3) ^ (r & 7)) << 3))];
    *(f16x8*)&op[(row0 + r) * 128 + c8] = vv;
  }
}

// ---------------- attn PASS 0, QBLK=64, grid 1024 (r20-verified, byte-identical)
__global__ __launch_bounds__(256, 2) void attn0_kernel(
    const f16* __restrict__ Qh, const f16* __restrict__ Kh,
    const f16* __restrict__ Vt, const int* __restrict__ mask,
    uint32_t* __restrict__ dump, float* __restrict__ outp)
{
  __shared__ f16 k_lds[64 * 128];   // 16 KB
  __shared__ f16 v_lds[128 * 64];   // 16 KB
  __shared__ f16 p_lds[4 * 16 * 72];// 9 KB
  __shared__ int m_lds[2][64 * 64]; // 32 KB raw mask tiles

  const int tid = threadIdx.x;
  const int u = blockIdx.x;
  const int qt = (u >> 3) & 15;
  const int b = ((u >> 7) << 3) | (u & 7);
  const int w = tid >> 6, l = tid & 63, lam = l & 15, g = l >> 4;
  const size_t batch_row = (size_t)b << 10;
  const f16* vtb = Vt + ((size_t)b << 17);

  f16x8 qf[4];
  {
    const f16* qbase = Qh + (batch_row + qt * 64 + w * 16 + lam) * 128;
#pragma unroll
    for (int kc = 0; kc < 4; ++kc) qf[kc] = *(const f16x8*)&qbase[kc * 32 + g * 8];
  }

  auto stageMask = [&](int kt_, int bu) {
#pragma unroll
    for (int it = 0; it < 4; ++it) {
      int slot0 = (w * 4 + it) * 64;
      int i = slot0 + l;
      int r = i >> 4, cd = i & 15;
      int cg = cd ^ (r & 7);
      glds16(mask + (batch_row + qt * 64 + r) * 1024 + kt_ * 64 + cg * 4,
             &m_lds[bu][slot0 * 4]);
    }
  };

  f32x4 acc[8] = {};
  float mrun[4], lrun[4];
#pragma unroll
  for (int i = 0; i < 4; ++i) { mrun[i] = -1e30f; lrun[i] = 0.f; }

  stageMask(0, 0); // prologue: tile-0 mask in flight

  int c = 0;
  for (int kt = 0; kt < 16; ++kt) {
    const int kb = kt * 64;
    __builtin_amdgcn_s_barrier(); // barrier1: exec-only

    { // stage K tile
      const f16* kbase = Kh + (batch_row + kb) * 128;
#pragma unroll
      for (int it = 0; it < 4; ++it) {
        int slot0 = (w * 4 + it) * 64;
        int i = slot0 + l;
        int r = i >> 4, ch = i & 15;
        glds16(kbase + r * 128 + ((ch ^ (r & 7)) << 3), &k_lds[slot0 * 8]);
      }
    }
    { // stage V^T tile
#pragma unroll
      for (int it = 0; it < 4; ++it) {
        int slot0 = (w * 4 + it) * 64;
        int i = slot0 + l;
        int r = i >> 3, ch = i & 7;
        glds16(vtb + r * 1024 + kb + ((ch ^ (r & 7)) << 3), &v_lds[slot0 * 8]);
      }
    }
    // issue next mask tile BEFORE barrier2 (kt==15: dummy, never read)
    stageMask(kt < 15 ? kt + 1 : 15, c ^ 1);

    // barrier2: drain store(kt-1)+KV(kt)+mask(kt), leave mask(kt+1) flying
    asm volatile("s_waitcnt vmcnt(4)" ::: "memory");
    __builtin_amdgcn_s_barrier();

    // QK^T
    f32x4 sv[4] = {};
    __builtin_amdgcn_s_setprio(1);
#pragma unroll
    for (int kc = 0; kc < 4; ++kc) {
#pragma unroll
      for (int cf = 0; cf < 4; ++cf) {
        int br = cf * 16 + lam;
        f16x8 bk = *(const f16x8*)&k_lds[br * 128 + (((4 * kc + g) ^ (br & 7)) << 3)];
        sv[cf] = __builtin_amdgcn_mfma_f32_16x16x32_f16(qf[kc], bk, sv[cf], 0, 0, 0);
      }
    }
    __builtin_amdgcn_s_setprio(0);

    // gather mask from raw int tile (swizzled read)
    uint32_t mk = 0;
#pragma unroll
    for (int cf = 0; cf < 4; ++cf)
#pragma unroll
      for (int ii = 0; ii < 4; ++ii) {
        int rt = w * 16 + g * 4 + ii;
        int cc = cf * 16 + lam;
        int mv = m_lds[c][rt * 64 + (cc ^ ((rt & 7) << 2))];
        mk |= (mv != 0 ? 1u : 0u) << (cf * 4 + ii);
      }

    // online softmax over kv cols (log2 space; lsum reduce deferred)
    float mrow4[4];
#pragma unroll
    for (int i = 0; i < 4; ++i) mrow4[i] = -1e30f;
#pragma unroll
    for (int cf = 0; cf < 4; ++cf)
#pragma unroll
      for (int i = 0; i < 4; ++i) {
        float v = sv[cf][i] * SCALE2;
        sv[cf][i] = v;
        mrow4[i] = fmaxf(mrow4[i], ((mk >> (cf * 4 + i)) & 1u) ? v : -1e30f);
      }
#pragma unroll
    for (int d = 1; d <= 8; d <<= 1)
#pragma unroll
      for (int i = 0; i < 4; ++i)
        mrow4[i] = fmaxf(mrow4[i], __shfl_xor(mrow4[i], d, 64));

    float sf[4], lsum[4];
#pragma unroll
    for (int i = 0; i < 4; ++i) {
      float mn = fmaxf(mrun[i], mrow4[i]);
      sf[i] = __builtin_amdgcn_exp2f(mrun[i] - mn);
      mrun[i] = mn;
      lsum[i] = 0.f;
    }
    f16* pslice = &p_lds[w * 1152];
#pragma unroll
    for (int cf = 0; cf < 4; ++cf)
#pragma unroll
      for (int i = 0; i < 4; ++i) {
        float p = ((mk >> (cf * 4 + i)) & 1u)
                      ? __builtin_amdgcn_exp2f(sv[cf][i] - mrun[i]) : 0.f;
        lsum[i] += p;
        int row = g * 4 + i;
        int cchunk = 2 * cf + (lam >> 3);
        pslice[row * 72 + (((cchunk ^ (row & 7)) << 3) | (lam & 7))] = (f16)p;
      }
#pragma unroll
    for (int i = 0; i < 4; ++i) lrun[i] = lrun[i] * sf[i] + lsum[i]; // per-lane partial
#pragma unroll
    for (int nf = 0; nf < 8; ++nf)
#pragma unroll
      for (int i = 0; i < 4; ++i) acc[nf][i] *= sf[i];

    // PV
    __builtin_amdgcn_s_setprio(1);
#pragma unroll
    for (int kc2 = 0; kc2 < 2; ++kc2) {
      f16x8 ap = *(const f16x8*)&pslice[lam * 72 + (((4 * kc2 + g) ^ (lam & 7)) << 3)];
#pragma unroll
      for (int nf = 0; nf < 8; ++nf) {
        int vr = nf * 16 + lam;
        f16x8 bv = *(const f16x8*)&v_lds[vr * 64 + (((kc2 * 4 + g) ^ (vr & 7)) << 3)];
        acc[nf] = __builtin_amdgcn_mfma_f32_16x16x32_f16(ap, bv, acc[nf], 0, 0, 0);
      }
    }
    __builtin_amdgcn_s_setprio(0);

    // dump raw mk pairs for pass 1 (off critical path; NT store)
    {
      uint32_t other = (uint32_t)__shfl_xor((int)mk, 1);
      if (!(l & 1))
        __builtin_nontemporal_store(
            (mk & 0xFFFFu) | (other << 16),
            &dump[(((size_t)b * 16 + qt) * 16 + kt) * 128 + (tid >> 1)]);
    }
    c ^= 1;
  }

  // deferred lsum cross-lane reduce
#pragma unroll
  for (int d = 1; d <= 8; d <<= 1)
#pragma unroll
    for (int i = 0; i < 4; ++i)
      lrun[i] += __shfl_xor(lrun[i], d, 64);

  float inv[4];
#pragma unroll
  for (int i = 0; i < 4; ++i) inv[i] = (lrun[i] > 0.f) ? 1.f / lrun[i] : 0.f;
  const size_t orow0 = batch_row + (size_t)qt * 64 + w * 16;
#pragma unroll
  for (int nf = 0; nf < 8; ++nf)
#pragma unroll
    for (int i = 0; i < 4; ++i)
      __builtin_nontemporal_store(acc[nf][i] * inv[i],
          &outp[(orow0 + g * 4 + i) * 128 + nf * 16 + lam]);
}

// ---------------- attn PASS 1, QBLK=128, grid 512 (r20-verified, byte-identical)
__global__ __launch_bounds__(256, 2) void attn1_kernel(
    const f16* __restrict__ Qh, const f16* __restrict__ Kh,
    const f16* __restrict__ Vt, const uint32_t* __restrict__ dump,
    float* __restrict__ outp)
{
  __shared__ f16 k_lds[64 * 128];
  __shared__ f16 v_lds[128 * 64];
  __shared__ f16 p_lds[8 * 16 * 72];
  __shared__ uint32_t mb[256];          // [h][128]

  const int tid = threadIdx.x;
  const int u = blockIdx.x;
  const int qt = (u >> 3) & 7;
  const int b = ((u >> 6) << 3) | (u & 7);
  const int w = tid >> 6, l = tid & 63, lam = l & 15, g = l >> 4;
  const size_t batch_row = (size_t)b << 10;

  f16x8 qf[2][4];
#pragma unroll
  for (int qd = 0; qd < 2; ++qd) {
    const f16* qbase = Qh + (batch_row + qt * 128 + w * 32 + qd * 16 + lam) * 128;
#pragma unroll
    for (int kc = 0; kc < 4; ++kc) qf[qd][kc] = *(const f16x8*)&qbase[kc * 32 + g * 8];
  }

  f32x4 acc[2][8] = {};
  float mrun[2][4], lrun[2][4];
#pragma unroll
  for (int qd = 0; qd < 2; ++qd)
#pragma unroll
    for (int i = 0; i < 4; ++i) { mrun[qd][i] = -1e30f; lrun[qd][i] = 0.f; }

  const f16* vtb = Vt + ((size_t)b << 17);

  for (int kt = 0; kt < 16; ++kt) {
    const int kb = kt * 64;
    __syncthreads();
    {
      const f16* kbase = Kh + (batch_row + kb) * 128;
#pragma unroll
      for (int it = 0; it < 4; ++it) {
        int slot0 = (w * 4 + it) * 64;
        int i = slot0 + l;
        int r = i >> 4, ch = i & 15;
        glds16(kbase + r * 128 + ((ch ^ (r & 7)) << 3), &k_lds[slot0 * 8]);
      }
    }
    {
#pragma unroll
      for (int it = 0; it < 4; ++it) {
        int slot0 = (w * 4 + it) * 64;
        int i = slot0 + l;
        int r = i >> 3, ch = i & 7;
        glds16(vtb + r * 1024 + kb + ((ch ^ (r & 7)) << 3), &v_lds[slot0 * 8]);
      }
    }
    { // stage mk-dump words: coalesced, lane-linear
      glds4(dump + ((((size_t)b * 16 + kt) * 16) + qt * 2 + (tid >> 7)) * 128 + (tid & 127),
            &mb[w * 64]);
    }
    __syncthreads();

#pragma unroll
    for (int qd = 0; qd < 2; ++qd) {
      f32x4 sv[4] = {};
      __builtin_amdgcn_s_setprio(1);
#pragma unroll
      for (int kc = 0; kc < 4; ++kc) {
#pragma unroll
        for (int cf = 0; cf < 4; ++cf) {
          int br = cf * 16 + lam;
          f16x8 bk = *(const f16x8*)&k_lds[br * 128 + (((4 * kc + g) ^ (br & 7)) << 3)];
          sv[cf] = __builtin_amdgcn_mfma_f32_16x16x32_f16(qf[qd][kc], bk, sv[cf], 0, 0, 0);
        }
      }
      __builtin_amdgcn_s_setprio(0);

      // gather from mk-dump
      uint32_t mk = 0;
      const int bit0 = ((w & 1) * 2 + qd) * 4 + (lam & 3);
#pragma unroll
      for (int cf = 0; cf < 4; ++cf) {
        int j = cf * 32 + (lam >> 2) * 8 + g * 2;
        uint32_t w0 = mb[(w >> 1) * 128 + j];
        uint32_t w1 = mb[(w >> 1) * 128 + j + 1];
        mk |= ((w0 >> bit0) & 1u) << (cf * 4 + 0);
        mk |= ((w0 >> (16 + bit0)) & 1u) << (cf * 4 + 1);
        mk |= ((w1 >> bit0) & 1u) << (cf * 4 + 2);
        mk |= ((w1 >> (16 + bit0)) & 1u) << (cf * 4 + 3);
      }

      float mrow4[4];
#pragma unroll
      for (int i = 0; i < 4; ++i) mrow4[i] = -1e30f;
#pragma unroll
      for (int cf = 0; cf < 4; ++cf)
#pragma unroll
        for (int i = 0; i < 4; ++i) {
          float v = sv[cf][i] * SCALE2;
          sv[cf][i] = v;
          mrow4[i] = fmaxf(mrow4[i], ((mk >> (cf * 4 + i)) & 1u) ? v : -1e30f);
        }
#pragma unroll
      for (int d = 1; d <= 8; d <<= 1)
#pragma unroll
        for (int i = 0; i < 4; ++i)
          mrow4[i] = fmaxf(mrow4[i], __shfl_xor(mrow4[i], d, 64));

      float sf[4], lsum[4];
#pragma unroll
      for (int i = 0; i < 4; ++i) {
        float mn = fmaxf(mrun[qd][i], mrow4[i]);
        sf[i] = __builtin_amdgcn_exp2f(mrun[qd][i] - mn);
        mrun[qd][i] = mn;
        lsum[i] = 0.f;
      }
      f16* pslice = &p_lds[(w * 2 + qd) * 1152];
#pragma unroll
      for (int cf = 0; cf < 4; ++cf)
#pragma unroll
        for (int i = 0; i < 4; ++i) {
          float p = ((mk >> (cf * 4 + i)) & 1u)
                        ? __builtin_amdgcn_exp2f(sv[cf][i] - mrun[qd][i]) : 0.f;
          lsum[i] += p;
          int row = g * 4 + i;
          int cchunk = 2 * cf + (lam >> 3);
          pslice[row * 72 + (((cchunk ^ (row & 7)) << 3) | (lam & 7))] = (f16)p;
        }
#pragma unroll
      for (int i = 0; i < 4; ++i) lrun[qd][i] = lrun[qd][i] * sf[i] + lsum[i];
#pragma unroll
      for (int nf = 0; nf < 8; ++nf)
#pragma unroll
        for (int i = 0; i < 4; ++i) acc[qd][nf][i] *= sf[i];
    }

    __builtin_amdgcn_s_setprio(1);
#pragma unroll
    for (int kc2 = 0; kc2 < 2; ++kc2) {
      f16x8 ap0 = *(const f16x8*)&p_lds[(w * 2 + 0) * 1152 + lam * 72 + (((4 * kc2 + g) ^ (lam & 7)) << 3)];
      f16x8 ap1 = *(const f16x8*)&p_lds[(w * 2 + 1) * 1152 + lam * 72 + (((4 * kc2 + g) ^ (lam & 7)) << 3)];
#pragma unroll
      for (int nf = 0; nf < 8; ++nf) {
        int vr = nf * 16 + lam;
        f16x8 bv = *(const f16x8*)&v_lds[vr * 64 + (((kc2 * 4 + g) ^ (vr & 7)) << 3)];
        acc[0][nf] = __builtin_amdgcn_mfma_f32_16x16x32_f16(ap0, bv, acc[0][nf], 0, 0, 0);
        acc[1][nf] = __builtin_amdgcn_mfma_f32_16x16x32_f16(ap1, bv, acc[1][nf], 0, 0, 0);
      }
    }
    __builtin_amdgcn_s_setprio(0);
  }

#pragma unroll
  for (int qd = 0; qd < 2; ++qd) {
#pragma unroll
    for (int d = 1; d <= 8; d <<= 1)
#pragma unroll
      for (int i = 0; i < 4; ++i)
        lrun[qd][i] += __shfl_xor(lrun[qd][i], d, 64);
    float inv[4];
#pragma unroll
    for (int i = 0; i < 4; ++i) inv[i] = (lrun[qd][i] > 0.f) ? 1.f / lrun[qd][i] : 0.f;
    const size_t orow0 = batch_row + (size_t)qt * 128 + w * 32 + qd * 16;
#pragma unroll
    for (int nf = 0; nf < 8; ++nf)
#pragma unroll
      for (int i = 0; i < 4; ++i)
        __builtin_nontemporal_store(acc[qd][nf][i] * inv[i],
            &outp[(orow0 + g * 4 + i) * 128 + nf * 16 + lam]);
  }
}

extern "C" void kernel_launch(void* const* d_in, const int* in_sizes, int n_in,
                              void* d_out, int out_size, void* d_ws, size_t ws_size,
                              hipStream_t stream) {
  const float* f1 = (const float*)d_in[0];
  const float* f2 = (const float*)d_in[1];
  const int* mask = (const int*)d_in[2];
  const float* W1 = (const float*)d_in[3];
  const float* b1 = (const float*)d_in[4];
  const float* W2 = (const float*)d_in[5];
  const float* b2 = (const float*)d_in[6];
  float* out = (float*)d_out;

  // ws: q_h(16MiB) k_h(16MiB) f1t(16MiB) dump(8MiB) = 56 MiB
  if (ws_size < (size_t)3 * 8388608 * sizeof(f16) + 8388608) return;

  f16* q_h = (f16*)d_ws;
  f16* k_h = q_h + 8388608;
  f16* f1t = k_h + 8388608;
  uint32_t* dump = (uint32_t*)(f1t + 8388608);
  // f2t lives in the out1 region of d_out: proj writes it; attn0 reads it;
  // attn1 overwrites that region afterwards (stream-ordered).
  f16* f2t = (f16*)d_out;

  proj_kernel<<<1024, 256, 0, stream>>>(f1, f2, W1, b1, W2, b2, q_h, k_h, f1t, f2t);
  // out layout: out1 [B,L2,F1] first, then out2 [B,L1,F2]
  attn0_kernel<<<1024, 256, 0, stream>>>(q_h, k_h, f2t, mask, dump, out + 8388608); // out2
  attn1_kernel<<<512, 256, 0, stream>>>(k_h, q_h, f1t, dump, out);                  // out1
}